// Round 6
// baseline (2968.016 us; speedup 1.0000x reference)
//
#include <hip/hip_runtime.h>
#include <math.h>

typedef unsigned short ushortT;
typedef unsigned int uintT;

using bf8   = __attribute__((ext_vector_type(8))) short;
using f32x4 = __attribute__((ext_vector_type(4))) float;

// ---------------- problem constants ----------------
// B=64, C=256, z=15x15, x=31x31, outputs on 17x17 grid.

// ws float offsets
#define SB_CLS 0
#define SB_REG 3072
#define SB_BT  6144
#define SB_CT  6656
#define WT_HI   ((size_t)8192)
#define WT_LO   (WT_HI + (size_t)1769472)
#define INT_SH  (WT_LO + (size_t)1769472)
#define INT_SL  (INT_SH + (size_t)7872512)
#define INT_ZH  (INT_SL + (size_t)7872512)
#define INT_ZL  (INT_ZH + (size_t)1843200)
#define WS_ZB   (INT_ZL + (size_t)1843200)              // f32 64*256*169
#define WS_XB   (WS_ZB + (size_t)2768896)               // f32 64*256*841
#define WS_RDW  (WS_XB + (size_t)13778944)              // f32 64*256*289
#define WS_CB   WS_XB                                   // cls tower feature reuses XB
// total ws floats = WS_RDW + 4734976 = 44,261,376 (~177 MB)

// d_out float offsets (x, cls, cls_dw, x_reg concatenated)
#define O_X    ((size_t)0)
#define O_CLS  ((size_t)73984)
#define O_CDW  ((size_t)92480)
#define O_XREG ((size_t)4827456)

// ---------------- helpers ----------------
__device__ __forceinline__ ushortT f2bf(float v) {
    uintT u = __float_as_uint(v);
    uintT r = ((u >> 16) & 1u) + 0x7fffu;   // round-to-nearest-even
    return (ushortT)((u + r) >> 16);
}
__device__ __forceinline__ float bf2f(ushortT h) {
    return __uint_as_float(((uintT)h) << 16);
}
__device__ __forceinline__ void gl16(const ushortT* g, ushortT* l) {
    __builtin_amdgcn_global_load_lds(
        (const __attribute__((address_space(1))) void*)g,
        (__attribute__((address_space(3))) void*)l, 16, 0, 0);
}

// ---------------- BN folding ----------------
__global__ void fold_bn_k(const float* __restrict__ cg, const float* __restrict__ cb,
                          const float* __restrict__ cm, const float* __restrict__ cv,
                          const float* __restrict__ rg, const float* __restrict__ rb,
                          const float* __restrict__ rm, const float* __restrict__ rv,
                          const float* __restrict__ btg, const float* __restrict__ btb,
                          const float* __restrict__ btm, const float* __restrict__ btv,
                          const float* __restrict__ ctg, const float* __restrict__ ctb,
                          const float* __restrict__ ctm, const float* __restrict__ ctv,
                          float* __restrict__ sb)
{
    int c = threadIdx.x; // 256
    for (int i = 0; i < 6; i++) {
        float s = cg[i*256 + c] * rsqrtf(cv[i*256 + c] + 1e-5f);
        sb[SB_CLS + i*512 + c]       = s;
        sb[SB_CLS + i*512 + 256 + c] = cb[i*256 + c] - cm[i*256 + c] * s;
        float s2 = rg[i*256 + c] * rsqrtf(rv[i*256 + c] + 1e-5f);
        sb[SB_REG + i*512 + c]       = s2;
        sb[SB_REG + i*512 + 256 + c] = rb[i*256 + c] - rm[i*256 + c] * s2;
    }
    float s = btg[c] * rsqrtf(btv[c] + 1e-5f);
    sb[SB_BT + c] = s; sb[SB_BT + 256 + c] = btb[c] - btm[c] * s;
    s = ctg[c] * rsqrtf(ctv[c] + 1e-5f);
    sb[SB_CT + c] = s; sb[SB_CT + 256 + c] = ctb[c] - ctm[c] * s;
}

// ---------------- NCHW f32 -> NHWC bf16 hi/lo planes ----------------
__global__ __launch_bounds__(256) void nchw2nhwc_split(
    const float* __restrict__ in, ushortT* __restrict__ hi, ushortT* __restrict__ lo, int HW)
{
    __shared__ float t[32][33];
    const int b = blockIdx.z, ci0 = blockIdx.y * 32, p0 = blockIdx.x * 32;
    const int tx = threadIdx.x, ty = threadIdx.y;
    for (int i = 0; i < 32; i += 8) {
        int ci = ci0 + ty + i, p = p0 + tx;
        t[ty + i][tx] = (p < HW) ? in[((size_t)(b * 256 + ci)) * HW + p] : 0.0f;
    }
    __syncthreads();
    for (int i = 0; i < 32; i += 8) {
        int p = p0 + ty + i;
        if (p < HW) {
            float v = t[tx][ty + i];
            ushortT h = f2bf(v);
            ushortT l = f2bf(v - bf2f(h));
            size_t o = ((size_t)b * HW + p) * 256 + ci0 + tx;
            hi[o] = h; lo[o] = l;
        }
    }
}

// ---------------- NCHW f32 17x17 -> padded 19x19 NHWC bf16 hi/lo (interior only) ----------------
__global__ __launch_bounds__(256) void nchw2nhwc_pad_split(
    const float* __restrict__ in, ushortT* __restrict__ hi, ushortT* __restrict__ lo)
{
    __shared__ float t[32][33];
    const int b = blockIdx.z, ci0 = blockIdx.y * 32, p0 = blockIdx.x * 32;
    const int tx = threadIdx.x, ty = threadIdx.y;
    for (int i = 0; i < 32; i += 8) {
        int ci = ci0 + ty + i, p = p0 + tx;
        t[ty + i][tx] = (p < 289) ? in[((size_t)(b * 256 + ci)) * 289 + p] : 0.0f;
    }
    __syncthreads();
    for (int i = 0; i < 32; i += 8) {
        int p = p0 + ty + i;
        if (p < 289) {
            float v = t[tx][ty + i];
            ushortT h = f2bf(v);
            ushortT l = f2bf(v - bf2f(h));
            int pp = (p / 17 + 1) * 19 + (p % 17 + 1);
            size_t o = ((size_t)b * 361 + pp) * 256 + ci0 + tx;
            hi[o] = h; lo[o] = l;
        }
    }
}

// ---------------- zero padded NHWC buffers ----------------
__global__ __launch_bounds__(256) void zero_pad_k(ushortT* __restrict__ hi, ushortT* __restrict__ lo)
{
    const size_t n16 = (size_t)64 * 361 * 256 / 8;  // uint4 count per plane
    uint4 z; z.x = z.y = z.z = z.w = 0u;
    uint4* h4 = (uint4*)hi; uint4* l4 = (uint4*)lo;
    for (size_t i = blockIdx.x * 256 + threadIdx.x; i < n16; i += (size_t)gridDim.x * 256) {
        h4[i] = z; l4[i] = z;
    }
}

// ---------------- weight transform: [co][ci][9] -> [co][kidx*256+ci] hi/lo ----------------
__global__ __launch_bounds__(256) void wt_split(
    const float* __restrict__ w, ushortT* __restrict__ whi, ushortT* __restrict__ wlo)
{
    const int co = blockIdx.x & 255, conv = blockIdx.x >> 8;
    const float* src = w + ((size_t)conv * 256 + co) * 2304;
    __shared__ float lw[2304];
    const int t = threadIdx.x;
#pragma unroll
    for (int i = 0; i < 9; i++) lw[i * 256 + t] = src[i * 256 + t];
    __syncthreads();
    size_t ob = ((size_t)conv * 256 + co) * 2304;
#pragma unroll
    for (int i = 0; i < 9; i++) {
        float v = lw[t * 9 + i];
        ushortT h = f2bf(v);
        whi[ob + i * 256 + t] = h;
        wlo[ob + i * 256 + t] = f2bf(v - bf2f(h));
    }
}

// ---------------- MFMA implicit-GEMM conv (VALID, dilated) + BN + relu ----------------
// A: in_t NHWC bf16 hi/lo [B][HI][WI][256]; B: wt [co][kidx*256+ci] hi/lo
// out f32 NCHW [B][256][Ho*Wo]. 1D grid = XT*2*64 blocks (XCD-swizzled), block 256 (4 waves).
// Split-bf16: acc += Ahi*Bhi + Ahi*Blo + Alo*Bhi  (near-f32 accuracy).
// 2-phase double-buffered pipeline, counted vmcnt (never 0 in the main loop).
// BK=32 chunks; 2-way-residual bank swizzle on 16B subchunks (free per m136).
template <int DH, int DW, int Ho, int Wo, int HI, int WI>
__global__ __launch_bounds__(256, 2) void mfma_conv(
    const ushortT* __restrict__ ahi, const ushortT* __restrict__ alo,
    const ushortT* __restrict__ whi, const ushortT* __restrict__ wlo,
    const float* __restrict__ sb, float* __restrict__ out)
{
    constexpr int NPOS = Ho * Wo;
    constexpr int XT = (NPOS + 127) / 128;
    constexpr int NBLK = XT * 2 * 64;
    constexpr int NCH = 72;                         // 9 kidx * 8 k-chunks of 32
    __shared__ __align__(16) ushortT lds[2][4][4096]; // [buf][plane A_hi,A_lo,B_hi,B_lo][128*32]

    const int tid = threadIdx.x, lane = tid & 63, wave = tid >> 6;

    // XCD-aware bijective swizzle (NBLK % 8 == 0)
    const int id = blockIdx.x;
    const int nid = (id & 7) * (NBLK >> 3) + (id >> 3);
    const int xt = nid % XT;
    const int rem = nid / XT;
    const int cog = rem & 1;
    const int b = rem >> 1;

    const int m0 = xt * 128;
    const int wrow = wave >> 1, wcol = wave & 1;

    // staging: q in {0,1}: row = q*64 + wave*16 + (lane>>2); stored 16B chunk = lane&3.
    // source pre-swizzle: chunk_src = (lane&3) ^ ((row>>1)&3); (row>>1)&3 == (lane>>3)&3 here.
    const int e8 = (((lane & 3) ^ ((lane >> 3) & 3))) * 8;
    size_t apb0, apb1, wpb0, wpb1;
    {
        int r0 = wave * 16 + (lane >> 2);
        int r1 = 64 + r0;
        int p0 = m0 + r0; if (p0 > NPOS - 1) p0 = NPOS - 1;
        int p1 = m0 + r1; if (p1 > NPOS - 1) p1 = NPOS - 1;
        int oh0 = p0 / Wo, ow0 = p0 - oh0 * Wo;
        int oh1 = p1 / Wo, ow1 = p1 - oh1 * Wo;
        apb0 = ((size_t)(b * HI + oh0) * WI + ow0) * 256 + e8;
        apb1 = ((size_t)(b * HI + oh1) * WI + ow1) * 256 + e8;
        wpb0 = (size_t)(cog * 128 + r0) * 2304 + e8;
        wpb1 = (size_t)(cog * 128 + r1) * 2304 + e8;
    }
    const int dst0 = wave * 16 * 32;                 // q=0 wave-uniform LDS ushort offset
    const int dst1 = 64 * 32 + dst0;                 // q=1

    auto STAGE = [&](int t, int bi) {
        const int kidx = t >> 3, s = t & 7;
        const int kh = (kidx * 11) >> 5;             // kidx/3 for kidx<9
        const int kw = kidx - 3 * kh;
        const int aoff = (DH * kh * WI + DW * kw) * 256 + s * 32;
        const int woff = kidx * 256 + s * 32;
        ushortT* L = &lds[bi][0][0];
        gl16(ahi + apb0 + aoff, L + dst0);
        gl16(ahi + apb1 + aoff, L + dst1);
        gl16(alo + apb0 + aoff, L + 4096 + dst0);
        gl16(alo + apb1 + aoff, L + 4096 + dst1);
        gl16(whi + wpb0 + woff, L + 8192 + dst0);
        gl16(whi + wpb1 + woff, L + 8192 + dst1);
        gl16(wlo + wpb0 + woff, L + 12288 + dst0);
        gl16(wlo + wpb1 + woff, L + 12288 + dst1);
    };

    f32x4 acc[4][4];
#pragma unroll
    for (int i = 0; i < 4; i++)
#pragma unroll
        for (int j = 0; j < 4; j++) acc[i][j] = (f32x4){0.f, 0.f, 0.f, 0.f};

    const int arow = lane & 15;
    const int ko = (((lane >> 4) ^ ((arow >> 1) & 3))) * 8;  // swizzled read chunk

    STAGE(0, 0);

#pragma unroll 1
    for (int t = 0; t < NCH; ++t) {
        const int cur = t & 1;
        if (t + 1 < NCH) {
            STAGE(t + 1, cur ^ 1);
            asm volatile("s_waitcnt vmcnt(8)" ::: "memory");   // wait only the 8 older loads
        } else {
            asm volatile("s_waitcnt vmcnt(0)" ::: "memory");
        }
        __builtin_amdgcn_s_barrier();
        __builtin_amdgcn_sched_barrier(0);   // fence: no ds_read hoist above barrier

        const ushortT* L = &lds[cur][0][0];
        bf8 ah[4], al[4], bh[4], bl[4];
#pragma unroll
        for (int mt = 0; mt < 4; ++mt) {
            int r = wrow * 64 + mt * 16 + arow;
            ah[mt] = *(const bf8*)(L + r * 32 + ko);
            al[mt] = *(const bf8*)(L + 4096 + r * 32 + ko);
        }
#pragma unroll
        for (int nt = 0; nt < 4; ++nt) {
            int r = wcol * 64 + nt * 16 + arow;
            bh[nt] = *(const bf8*)(L + 8192 + r * 32 + ko);
            bl[nt] = *(const bf8*)(L + 12288 + r * 32 + ko);
        }
#pragma unroll
        for (int mt = 0; mt < 4; ++mt)
#pragma unroll
            for (int nt = 0; nt < 4; ++nt) {
                acc[mt][nt] = __builtin_amdgcn_mfma_f32_16x16x32_bf16(ah[mt], bh[nt], acc[mt][nt], 0, 0, 0);
                acc[mt][nt] = __builtin_amdgcn_mfma_f32_16x16x32_bf16(ah[mt], bl[nt], acc[mt][nt], 0, 0, 0);
                acc[mt][nt] = __builtin_amdgcn_mfma_f32_16x16x32_bf16(al[mt], bh[nt], acc[mt][nt], 0, 0, 0);
            }
        __builtin_amdgcn_sched_barrier(0);   // keep reads/MFMA above the release barrier
        __builtin_amdgcn_s_barrier();        // buf[cur] free for overwrite next iter
    }

    // epilogue: folded BN + relu, f32 NCHW store
#pragma unroll
    for (int nt = 0; nt < 4; ++nt) {
        const int co = cog * 128 + wcol * 64 + nt * 16 + arow;
        const float scl = sb[co], bia = sb[256 + co];
        const size_t ob = ((size_t)b * 256 + co) * NPOS;
#pragma unroll
        for (int mt = 0; mt < 4; ++mt)
#pragma unroll
            for (int r = 0; r < 4; ++r) {
                int p = m0 + wrow * 64 + mt * 16 + (lane >> 4) * 4 + r;
                if (p < NPOS) {
                    float v = fmaf(acc[mt][nt][r], scl, bia);
                    out[ob + p] = v > 0.f ? v : 0.f;
                }
            }
    }
}

// ---------------- depthwise xcorr (one of 3), softmax-weighted accumulate ----------------
template <int HZ_, int WZ_, int WX_, int IDX>
__global__ __launch_bounds__(192) void xcorr_one(
    const float* __restrict__ z, const float* __restrict__ x,
    const float* __restrict__ w3, float* __restrict__ out)
{
    constexpr int HX_ = 16 + HZ_;
    constexpr int NX = HX_ * WX_;
    constexpr int NZ = HZ_ * WZ_;
    __shared__ float xs[NX + 4];
    __shared__ float zs[NZ];
    const int bc = blockIdx.x;
    const float* xp = x + (size_t)bc * NX;
    const float* zp = z + (size_t)bc * NZ;
    for (int i = threadIdx.x; i < NX; i += 192) xs[i] = xp[i];
    for (int i = threadIdx.x; i < NZ; i += 192) zs[i] = zp[i];

    float a = w3[0], b = w3[1], c = w3[2];
    float mx = fmaxf(a, fmaxf(b, c));
    float e0 = expf(a - mx), e1 = expf(b - mx), e2 = expf(c - mx);
    float wt = (IDX == 0 ? e0 : (IDX == 1 ? e1 : e2)) / (e0 + e1 + e2);
    __syncthreads();

    int t = threadIdx.x;
    if (t >= 153) return;
    int oh = t / 9, owp = t % 9, ow0 = owp * 2;
    float s0 = 0.0f, s1 = 0.0f;
#pragma unroll 1
    for (int kh = 0; kh < HZ_; kh++) {
        const float* xr = &xs[(oh + kh) * WX_ + ow0];
        const float* zr = &zs[kh * WZ_];
#pragma unroll
        for (int kw = 0; kw < WZ_; kw++) {
            float zv = zr[kw];
            s0 = fmaf(xr[kw], zv, s0);
            s1 = fmaf(xr[kw + 1], zv, s1);
        }
    }
    size_t o = (size_t)bc * 289 + oh * 17 + ow0;
    if (IDX == 0) {
        out[o] = wt * s0;
        if (owp < 8) out[o + 1] = wt * s1;
    } else {
        out[o] += wt * s0;
        if (owp < 8) out[o + 1] += wt * s1;
    }
}

// ---------------- bbox pred: conv 3x3 pad1 C->4 (LDS-staged), exp epilogue ----------------
__global__ __launch_bounds__(320) void bp_pred(
    const float* __restrict__ xr, const float* __restrict__ w,
    const float* __restrict__ wb, const float* __restrict__ adj,
    const float* __restrict__ bia, float* __restrict__ outx)
{
    __shared__ float pl[16 * 289];
    __shared__ float wl[16 * 36];
    const int b = blockIdx.x, tid = threadIdx.x;
    const int p = tid;
    const int oh = p / 17, ow = p % 17;
    int ihs[3], iws[3]; bool okh[3], okw[3];
#pragma unroll
    for (int k = 0; k < 3; k++) {
        int ih = oh - 1 + k; okh[k] = (unsigned)ih < 17u; ihs[k] = okh[k] ? ih : 0;
        int iw = ow - 1 + k; okw[k] = (unsigned)iw < 17u; iws[k] = okw[k] ? iw : 0;
    }
    float acc0 = 0.f, acc1 = 0.f, acc2 = 0.f, acc3 = 0.f;
    const float* xb = xr + (size_t)b * 256 * 289;
#pragma unroll 1
    for (int c0 = 0; c0 < 256; c0 += 16) {
        __syncthreads();
        for (int i = tid; i < 16 * 289; i += 320) pl[i] = xb[(size_t)c0 * 289 + i];
        for (int i = tid; i < 576; i += 320) {
            int ci = i / 36, r = i - ci * 36;
            int co = r / 9, k = r - co * 9;
            wl[ci * 36 + k * 4 + co] = w[((size_t)co * 256 + c0 + ci) * 9 + k];
        }
        __syncthreads();
        if (p < 289) {
#pragma unroll 1
            for (int ci = 0; ci < 16; ci++) {
                const float* plane = &pl[ci * 289];
                const float* wr = &wl[ci * 36];
#pragma unroll
                for (int kh = 0; kh < 3; kh++)
#pragma unroll
                    for (int kw = 0; kw < 3; kw++) {
                        float v = plane[ihs[kh] * 17 + iws[kw]];
                        v = (okh[kh] && okw[kw]) ? v : 0.0f;
                        const float* wk = &wr[(kh * 3 + kw) * 4];
                        acc0 = fmaf(v, wk[0], acc0);
                        acc1 = fmaf(v, wk[1], acc1);
                        acc2 = fmaf(v, wk[2], acc2);
                        acc3 = fmaf(v, wk[3], acc3);
                    }
            }
        }
    }
    if (p < 289) {
        float ad = adj[0];
        float t0 = fmaf(ad, acc0 + wb[0], bia[0]);
        float t1 = fmaf(ad, acc1 + wb[1], bia[1]);
        float t2 = fmaf(ad, acc2 + wb[2], bia[2]);
        float t3 = fmaf(ad, acc3 + wb[3], bia[3]);
        size_t ob = (size_t)b * 4 * 289 + p;
        outx[ob]           = expf(fminf(t0, 4.7f));
        outx[ob + 289]     = expf(fminf(t1, 4.7f));
        outx[ob + 2 * 289] = expf(fminf(t2, 4.7f));
        outx[ob + 3 * 289] = expf(fminf(t3, 4.7f));
    }
}

// ---------------- cls pred: conv 3x3 pad1 C->1 (LDS-staged) ----------------
__global__ __launch_bounds__(320) void cp_pred(
    const float* __restrict__ cfeat, const float* __restrict__ w,
    const float* __restrict__ wb, float* __restrict__ outc)
{
    __shared__ float pl[16 * 289];
    __shared__ float wl[16 * 9];
    const int b = blockIdx.x, tid = threadIdx.x;
    const int p = tid;
    const int oh = p / 17, ow = p % 17;
    int ihs[3], iws[3]; bool okh[3], okw[3];
#pragma unroll
    for (int k = 0; k < 3; k++) {
        int ih = oh - 1 + k; okh[k] = (unsigned)ih < 17u; ihs[k] = okh[k] ? ih : 0;
        int iw = ow - 1 + k; okw[k] = (unsigned)iw < 17u; iws[k] = okw[k] ? iw : 0;
    }
    float acc = 0.f;
    const float* xb = cfeat + (size_t)b * 256 * 289;
#pragma unroll 1
    for (int c0 = 0; c0 < 256; c0 += 16) {
        __syncthreads();
        for (int i = tid; i < 16 * 289; i += 320) pl[i] = xb[(size_t)c0 * 289 + i];
        for (int i = tid; i < 144; i += 320) {
            int ci = i / 9, k = i - ci * 9;
            wl[ci * 9 + k] = w[((size_t)(c0 + ci)) * 9 + k];
        }
        __syncthreads();
        if (p < 289) {
#pragma unroll 1
            for (int ci = 0; ci < 16; ci++) {
                const float* plane = &pl[ci * 289];
                const float* wr = &wl[ci * 9];
#pragma unroll
                for (int kh = 0; kh < 3; kh++)
#pragma unroll
                    for (int kw = 0; kw < 3; kw++) {
                        float v = plane[ihs[kh] * 17 + iws[kw]];
                        v = (okh[kh] && okw[kw]) ? v : 0.0f;
                        acc = fmaf(v, wr[kh * 3 + kw], acc);
                    }
            }
        }
    }
    if (p < 289) outc[(size_t)b * 289 + p] = 0.1f * (acc + wb[0]);
}

// ---------------- host launch ----------------
extern "C" void kernel_launch(void* const* d_in, const int* in_sizes, int n_in,
                              void* d_out, int out_size, void* d_ws, size_t ws_size,
                              hipStream_t stream)
{
    (void)in_sizes; (void)n_in; (void)out_size; (void)ws_size;
    const float* search = (const float*)d_in[0];
    const float* kern   = (const float*)d_in[1];
    const float* cls_mw = (const float*)d_in[2];
    const float* reg_mw = (const float*)d_in[7];
    const float* cls_dww = (const float*)d_in[12];
    const float* reg_dww = (const float*)d_in[13];
    const float* btw = (const float*)d_in[14];
    const float* ctw = (const float*)d_in[19];
    const float* bpw = (const float*)d_in[24];
    const float* bpb = (const float*)d_in[25];
    const float* cpw = (const float*)d_in[26];
    const float* cpb = (const float*)d_in[27];
    const float* adj = (const float*)d_in[28];
    const float* bia = (const float*)d_in[29];

    float* ws  = (float*)d_ws;
    float* out = (float*)d_out;

    ushortT* wt_hi = (ushortT*)(ws + WT_HI);
    ushortT* wt_lo = (ushortT*)(ws + WT_LO);
    ushortT* s_hi  = (ushortT*)(ws + INT_SH);
    ushortT* s_lo  = (ushortT*)(ws + INT_SL);
    ushortT* z_hi  = (ushortT*)(ws + INT_ZH);
    ushortT* z_lo  = (ushortT*)(ws + INT_ZL);
    // tower-phase aliases (search NHWC + wt regions dead by then)
    ushortT* pad_hi = s_hi;
    ushortT* pad_lo = s_lo;

    fold_bn_k<<<1, 256, 0, stream>>>(
        (const float*)d_in[3], (const float*)d_in[4], (const float*)d_in[5], (const float*)d_in[6],
        (const float*)d_in[8], (const float*)d_in[9], (const float*)d_in[10], (const float*)d_in[11],
        (const float*)d_in[15], (const float*)d_in[16], (const float*)d_in[17], (const float*)d_in[18],
        (const float*)d_in[20], (const float*)d_in[21], (const float*)d_in[22], (const float*)d_in[23],
        ws);

    // input transforms (shared across both branches)
    nchw2nhwc_split<<<dim3(31, 8, 64), dim3(32, 8), 0, stream>>>(search, s_hi, s_lo, 961);
    nchw2nhwc_split<<<dim3(8, 8, 64), dim3(32, 8), 0, stream>>>(kern, z_hi, z_lo, 225);

    const size_t WC = (size_t)2304 * 256; // per-conv wt plane stride (ushorts)

    auto branch = [&](const float* mw, const float* sbb, const float* dww, float* dwout) {
        wt_split<<<1536, 256, 0, stream>>>(mw, wt_hi, wt_lo);
        // pair 0: dil (1,1): z 13x13, x 29x29
        mfma_conv<1, 1, 13, 13, 15, 15><<<256, 256, 0, stream>>>(
            z_hi, z_lo, wt_hi + 0 * WC, wt_lo + 0 * WC, sbb + 0 * 512, ws + WS_ZB);
        mfma_conv<1, 1, 29, 29, 31, 31><<<896, 256, 0, stream>>>(
            s_hi, s_lo, wt_hi + 1 * WC, wt_lo + 1 * WC, sbb + 1 * 512, ws + WS_XB);
        xcorr_one<13, 13, 29, 0><<<16384, 192, 0, stream>>>(ws + WS_ZB, ws + WS_XB, dww, dwout);
        // pair 1: dil (2,1): z 11x13, x 27x29
        mfma_conv<2, 1, 11, 13, 15, 15><<<256, 256, 0, stream>>>(
            z_hi, z_lo, wt_hi + 2 * WC, wt_lo + 2 * WC, sbb + 2 * 512, ws + WS_ZB);
        mfma_conv<2, 1, 27, 29, 31, 31><<<896, 256, 0, stream>>>(
            s_hi, s_lo, wt_hi + 3 * WC, wt_lo + 3 * WC, sbb + 3 * 512, ws + WS_XB);
        xcorr_one<11, 13, 29, 1><<<16384, 192, 0, stream>>>(ws + WS_ZB, ws + WS_XB, dww, dwout);
        // pair 2: dil (1,2): z 13x11, x 29x27
        mfma_conv<1, 2, 13, 11, 15, 15><<<256, 256, 0, stream>>>(
            z_hi, z_lo, wt_hi + 4 * WC, wt_lo + 4 * WC, sbb + 4 * 512, ws + WS_ZB);
        mfma_conv<1, 2, 29, 27, 31, 31><<<896, 256, 0, stream>>>(
            s_hi, s_lo, wt_hi + 5 * WC, wt_lo + 5 * WC, sbb + 5 * 512, ws + WS_XB);
        xcorr_one<13, 11, 27, 2><<<16384, 192, 0, stream>>>(ws + WS_ZB, ws + WS_XB, dww, dwout);
    };

    // cls branch -> cls_dw directly in d_out; reg branch -> ws
    branch(cls_mw, ws + SB_CLS, cls_dww, out + O_CDW);
    branch(reg_mw, ws + SB_REG, reg_dww, ws + WS_RDW);

    // ---- towers (MFMA path): search NHWC + wt regions now dead, reuse them ----
    wt_split<<<256, 256, 0, stream>>>(btw, wt_hi, wt_lo);                 // slot 0 = bt
    wt_split<<<256, 256, 0, stream>>>(ctw, wt_hi + WC, wt_lo + WC);       // slot 1 = ct
    zero_pad_k<<<1024, 256, 0, stream>>>(pad_hi, pad_lo);

    // bbox tower: pad(reg_dw) -> mfma conv -> x_reg (d_out), then bp conv + exp -> x (d_out)
    nchw2nhwc_pad_split<<<dim3(10, 8, 64), dim3(32, 8), 0, stream>>>(ws + WS_RDW, pad_hi, pad_lo);
    mfma_conv<1, 1, 17, 17, 19, 19><<<384, 256, 0, stream>>>(
        pad_hi, pad_lo, wt_hi, wt_lo, ws + SB_BT, out + O_XREG);
    bp_pred<<<64, 320, 0, stream>>>(out + O_XREG, bpw, bpb, adj, bia, out + O_X);

    // cls tower: pad(cls_dw) -> mfma conv -> c (ws), then cp conv -> cls (d_out)
    // (border zeros persist from zero_pad_k; interior fully rewritten)
    nchw2nhwc_pad_split<<<dim3(10, 8, 64), dim3(32, 8), 0, stream>>>(out + O_CDW, pad_hi, pad_lo);
    mfma_conv<1, 1, 17, 17, 19, 19><<<384, 256, 0, stream>>>(
        pad_hi, pad_lo, wt_hi + WC, wt_lo + WC, ws + SB_CT, ws + WS_CB);
    cp_pred<<<64, 320, 0, stream>>>(ws + WS_CB, cpw, cpb, out + O_CLS);
}

// Round 8
// 2756.834 us; speedup vs baseline: 1.0766x; 1.0766x over previous
//
#include <hip/hip_runtime.h>
#include <math.h>

typedef unsigned short ushortT;
typedef unsigned int uintT;

using bf8   = __attribute__((ext_vector_type(8))) short;
using f32x4 = __attribute__((ext_vector_type(4))) float;

// ---------------- problem constants ----------------
// B=64, C=256, z=15x15, x=31x31, outputs on 17x17 grid.

// ws float offsets
#define SB_CLS 0
#define SB_REG 3072
#define SB_BT  6144
#define SB_CT  6656
#define WT_HI   ((size_t)8192)
#define WT_LO   (WT_HI + (size_t)1769472)               // unused (2-term split), kept for layout
#define INT_SH  (WT_LO + (size_t)1769472)
#define INT_SL  (INT_SH + (size_t)7872512)
#define INT_ZH  (INT_SL + (size_t)7872512)
#define INT_ZL  (INT_ZH + (size_t)1843200)
#define WS_ZB   (INT_ZL + (size_t)1843200)              // f32 64*256*169
#define WS_XB   (WS_ZB + (size_t)2768896)               // f32 64*256*841
#define WS_RDW  (WS_XB + (size_t)13778944)              // f32 64*256*289
#define WS_CB   WS_XB                                   // cls tower feature reuses XB
// total ws floats = WS_RDW + 4734976 = 44,261,376 (~177 MB)

// d_out float offsets (x, cls, cls_dw, x_reg concatenated)
#define O_X    ((size_t)0)
#define O_CLS  ((size_t)73984)
#define O_CDW  ((size_t)92480)
#define O_XREG ((size_t)4827456)

// ---------------- helpers ----------------
__device__ __forceinline__ ushortT f2bf(float v) {
    uintT u = __float_as_uint(v);
    uintT r = ((u >> 16) & 1u) + 0x7fffu;   // round-to-nearest-even
    return (ushortT)((u + r) >> 16);
}
__device__ __forceinline__ float bf2f(ushortT h) {
    return __uint_as_float(((uintT)h) << 16);
}
__device__ __forceinline__ void gl16(const ushortT* g, ushortT* l) {
    __builtin_amdgcn_global_load_lds(
        (const __attribute__((address_space(1))) void*)g,
        (__attribute__((address_space(3))) void*)l, 16, 0, 0);
}

// ---------------- BN folding ----------------
__global__ void fold_bn_k(const float* __restrict__ cg, const float* __restrict__ cb,
                          const float* __restrict__ cm, const float* __restrict__ cv,
                          const float* __restrict__ rg, const float* __restrict__ rb,
                          const float* __restrict__ rm, const float* __restrict__ rv,
                          const float* __restrict__ btg, const float* __restrict__ btb,
                          const float* __restrict__ btm, const float* __restrict__ btv,
                          const float* __restrict__ ctg, const float* __restrict__ ctb,
                          const float* __restrict__ ctm, const float* __restrict__ ctv,
                          float* __restrict__ sb)
{
    int c = threadIdx.x; // 256
    for (int i = 0; i < 6; i++) {
        float s = cg[i*256 + c] * rsqrtf(cv[i*256 + c] + 1e-5f);
        sb[SB_CLS + i*512 + c]       = s;
        sb[SB_CLS + i*512 + 256 + c] = cb[i*256 + c] - cm[i*256 + c] * s;
        float s2 = rg[i*256 + c] * rsqrtf(rv[i*256 + c] + 1e-5f);
        sb[SB_REG + i*512 + c]       = s2;
        sb[SB_REG + i*512 + 256 + c] = rb[i*256 + c] - rm[i*256 + c] * s2;
    }
    float s = btg[c] * rsqrtf(btv[c] + 1e-5f);
    sb[SB_BT + c] = s; sb[SB_BT + 256 + c] = btb[c] - btm[c] * s;
    s = ctg[c] * rsqrtf(ctv[c] + 1e-5f);
    sb[SB_CT + c] = s; sb[SB_CT + 256 + c] = ctb[c] - ctm[c] * s;
}

// ---------------- NCHW f32 -> NHWC bf16 hi/lo planes ----------------
__global__ __launch_bounds__(256) void nchw2nhwc_split(
    const float* __restrict__ in, ushortT* __restrict__ hi, ushortT* __restrict__ lo, int HW)
{
    __shared__ float t[32][33];
    const int b = blockIdx.z, ci0 = blockIdx.y * 32, p0 = blockIdx.x * 32;
    const int tx = threadIdx.x, ty = threadIdx.y;
    for (int i = 0; i < 32; i += 8) {
        int ci = ci0 + ty + i, p = p0 + tx;
        t[ty + i][tx] = (p < HW) ? in[((size_t)(b * 256 + ci)) * HW + p] : 0.0f;
    }
    __syncthreads();
    for (int i = 0; i < 32; i += 8) {
        int p = p0 + ty + i;
        if (p < HW) {
            float v = t[tx][ty + i];
            ushortT h = f2bf(v);
            ushortT l = f2bf(v - bf2f(h));
            size_t o = ((size_t)b * HW + p) * 256 + ci0 + tx;
            hi[o] = h; lo[o] = l;
        }
    }
}

// ---------------- NCHW f32 17x17 -> padded 19x19 NHWC bf16 hi/lo (interior only) ----------------
__global__ __launch_bounds__(256) void nchw2nhwc_pad_split(
    const float* __restrict__ in, ushortT* __restrict__ hi, ushortT* __restrict__ lo)
{
    __shared__ float t[32][33];
    const int b = blockIdx.z, ci0 = blockIdx.y * 32, p0 = blockIdx.x * 32;
    const int tx = threadIdx.x, ty = threadIdx.y;
    for (int i = 0; i < 32; i += 8) {
        int ci = ci0 + ty + i, p = p0 + tx;
        t[ty + i][tx] = (p < 289) ? in[((size_t)(b * 256 + ci)) * 289 + p] : 0.0f;
    }
    __syncthreads();
    for (int i = 0; i < 32; i += 8) {
        int p = p0 + ty + i;
        if (p < 289) {
            float v = t[tx][ty + i];
            ushortT h = f2bf(v);
            ushortT l = f2bf(v - bf2f(h));
            int pp = (p / 17 + 1) * 19 + (p % 17 + 1);
            size_t o = ((size_t)b * 361 + pp) * 256 + ci0 + tx;
            hi[o] = h; lo[o] = l;
        }
    }
}

// ---------------- zero padded NHWC buffers ----------------
__global__ __launch_bounds__(256) void zero_pad_k(ushortT* __restrict__ hi, ushortT* __restrict__ lo)
{
    const size_t n16 = (size_t)64 * 361 * 256 / 8;  // uint4 count per plane
    uint4 z; z.x = z.y = z.z = z.w = 0u;
    uint4* h4 = (uint4*)hi; uint4* l4 = (uint4*)lo;
    for (size_t i = blockIdx.x * 256 + threadIdx.x; i < n16; i += (size_t)gridDim.x * 256) {
        h4[i] = z; l4[i] = z;
    }
}

// ---------------- weight transform: [co][ci][9] -> [co][kidx*256+ci] hi only ----------------
__global__ __launch_bounds__(256) void wt_split(
    const float* __restrict__ w, ushortT* __restrict__ whi)
{
    const int co = blockIdx.x & 255, conv = blockIdx.x >> 8;
    const float* src = w + ((size_t)conv * 256 + co) * 2304;
    __shared__ float lw[2304];
    const int t = threadIdx.x;
#pragma unroll
    for (int i = 0; i < 9; i++) lw[i * 256 + t] = src[i * 256 + t];
    __syncthreads();
    size_t ob = ((size_t)conv * 256 + co) * 2304;
#pragma unroll
    for (int i = 0; i < 9; i++)
        whi[ob + i * 256 + t] = f2bf(lw[t * 9 + i]);
}

// ---------------- MFMA implicit-GEMM conv (VALID, dilated) + BN + relu ----------------
// A: in_t NHWC bf16 hi/lo [B][HI][WI][256]; B: wt [co][kidx*256+ci] hi
// out f32 NCHW [B][256][Ho*Wo]. 1D grid = XT*2*64 blocks (XCD-swizzled), block 256 (4 waves).
// 2-term split: acc += Ahi*Bhi + Alo*Bhi  (A near-f32; B bf16, rel err ~2^-9).
// Round-5 proven structure: BK=64, single buffer, 2 __syncthreads per chunk.
// T2: 16B-chunk XOR swizzle (source-side pre-swizzle for global_load_lds; XOR on ds_read).
template <int DH, int DW, int Ho, int Wo, int HI, int WI>
__global__ __launch_bounds__(256, 3) void mfma_conv(
    const ushortT* __restrict__ ahi, const ushortT* __restrict__ alo,
    const ushortT* __restrict__ whi,
    const float* __restrict__ sb, float* __restrict__ out)
{
    constexpr int NPOS = Ho * Wo;
    constexpr int XT = (NPOS + 127) / 128;
    constexpr int NBLK = XT * 2 * 64;
    __shared__ __align__(16) ushortT lds[3][8192];   // planes A_hi, A_lo, B_hi: [128 rows][64 k]

    const int t = threadIdx.x, lane = t & 63, wave = t >> 6;

    // XCD-aware bijective swizzle (NBLK % 8 == 0): each XCD gets a contiguous nid range.
    const int id = blockIdx.x;
    const int nid = (id & 7) * (NBLK >> 3) + (id >> 3);
    const int xt = nid % XT;
    const int rem = nid / XT;
    const int cog = rem & 1;
    const int b = rem >> 1;

    const int m0 = xt * 128;
    const int wrow = wave >> 1, wcol = wave & 1;

    // staging: for q in 0..3, row = q*32 + wave*8 + (lane>>3); stored 16B-chunk = lane&7.
    // Source chunk pre-swizzled: g = (lane&7) ^ (row&7), row&7 == lane>>3 here.
    const int lrow = lane >> 3;
    const int e8 = (((lane & 7) ^ lrow) & 7) * 8;
    int aoh[4], aow[4];
    size_t wrb[4];
#pragma unroll
    for (int q = 0; q < 4; q++) {
        int r = q * 32 + wave * 8 + lrow;
        int p = m0 + r; if (p > NPOS - 1) p = NPOS - 1;
        aoh[q] = p / Wo; aow[q] = p - aoh[q] * Wo;
        wrb[q] = (size_t)(cog * 128 + r) * 2304 + e8;
    }

    f32x4 acc[4][4];
#pragma unroll
    for (int i = 0; i < 4; i++)
#pragma unroll
        for (int j = 0; j < 4; j++) acc[i][j] = (f32x4){0.f, 0.f, 0.f, 0.f};

    const int arow = lane & 15;
    const int sw = arow & 7;                 // read-side XOR (row&7, constant across mt/nt)
    const int lsel = lane >> 4;              // k sub-run selector

#pragma unroll 1
    for (int kidx = 0; kidx < 9; ++kidx) {
        const int kh = kidx / 3, kw = kidx - kh * 3;
        size_t ab[4];
#pragma unroll
        for (int q = 0; q < 4; q++)
            ab[q] = ((size_t)((b * HI) + aoh[q] + DH * kh) * WI + aow[q] + DW * kw) * 256 + e8;
        const size_t wk = (size_t)kidx * 256;
#pragma unroll 1
        for (int s = 0; s < 4; ++s) {
            const int cs = s * 64;
#pragma unroll
            for (int q = 0; q < 4; q++) {
                const int dst = (q * 32 + wave * 8) * 64;   // wave-uniform; HW adds lane*16B
                gl16(ahi + ab[q] + cs, &lds[0][dst]);
                gl16(alo + ab[q] + cs, &lds[1][dst]);
                gl16(whi + wrb[q] + wk + cs, &lds[2][dst]);
            }
            __syncthreads();
#pragma unroll
            for (int kk = 0; kk < 2; ++kk) {
                const int koS = (((kk * 4 + lsel) ^ sw) << 3);   // swizzled chunk
                bf8 ah[4], al[4], bh[4];
#pragma unroll
                for (int mt = 0; mt < 4; ++mt) {
                    int r = wrow * 64 + mt * 16 + arow;
                    ah[mt] = *(const bf8*)&lds[0][r * 64 + koS];
                    al[mt] = *(const bf8*)&lds[1][r * 64 + koS];
                }
#pragma unroll
                for (int nt = 0; nt < 4; ++nt) {
                    int r = wcol * 64 + nt * 16 + arow;
                    bh[nt] = *(const bf8*)&lds[2][r * 64 + koS];
                }
#pragma unroll
                for (int mt = 0; mt < 4; ++mt)
#pragma unroll
                    for (int nt = 0; nt < 4; ++nt) {
                        acc[mt][nt] = __builtin_amdgcn_mfma_f32_16x16x32_bf16(ah[mt], bh[nt], acc[mt][nt], 0, 0, 0);
                        acc[mt][nt] = __builtin_amdgcn_mfma_f32_16x16x32_bf16(al[mt], bh[nt], acc[mt][nt], 0, 0, 0);
                    }
            }
            __syncthreads();
        }
    }

    // epilogue: folded BN + relu, f32 NCHW store
#pragma unroll
    for (int nt = 0; nt < 4; ++nt) {
        const int co = cog * 128 + wcol * 64 + nt * 16 + arow;
        const float scl = sb[co], bia = sb[256 + co];
        const size_t ob = ((size_t)b * 256 + co) * NPOS;
#pragma unroll
        for (int mt = 0; mt < 4; ++mt)
#pragma unroll
            for (int r = 0; r < 4; ++r) {
                int p = m0 + wrow * 64 + mt * 16 + (lane >> 4) * 4 + r;
                if (p < NPOS) {
                    float v = fmaf(acc[mt][nt][r], scl, bia);
                    out[ob + p] = v > 0.f ? v : 0.f;
                }
            }
    }
}

// ---------------- depthwise xcorr (one of 3), softmax-weighted accumulate ----------------
template <int HZ_, int WZ_, int WX_, int IDX>
__global__ __launch_bounds__(192) void xcorr_one(
    const float* __restrict__ z, const float* __restrict__ x,
    const float* __restrict__ w3, float* __restrict__ out)
{
    constexpr int HX_ = 16 + HZ_;
    constexpr int NX = HX_ * WX_;
    constexpr int NZ = HZ_ * WZ_;
    __shared__ float xs[NX + 4];
    __shared__ float zs[NZ];
    const int bc = blockIdx.x;
    const float* xp = x + (size_t)bc * NX;
    const float* zp = z + (size_t)bc * NZ;
    for (int i = threadIdx.x; i < NX; i += 192) xs[i] = xp[i];
    for (int i = threadIdx.x; i < NZ; i += 192) zs[i] = zp[i];

    float a = w3[0], b = w3[1], c = w3[2];
    float mx = fmaxf(a, fmaxf(b, c));
    float e0 = expf(a - mx), e1 = expf(b - mx), e2 = expf(c - mx);
    float wt = (IDX == 0 ? e0 : (IDX == 1 ? e1 : e2)) / (e0 + e1 + e2);
    __syncthreads();

    int t = threadIdx.x;
    if (t >= 153) return;
    int oh = t / 9, owp = t % 9, ow0 = owp * 2;
    float s0 = 0.0f, s1 = 0.0f;
#pragma unroll 1
    for (int kh = 0; kh < HZ_; kh++) {
        const float* xr = &xs[(oh + kh) * WX_ + ow0];
        const float* zr = &zs[kh * WZ_];
#pragma unroll
        for (int kw = 0; kw < WZ_; kw++) {
            float zv = zr[kw];
            s0 = fmaf(xr[kw], zv, s0);
            s1 = fmaf(xr[kw + 1], zv, s1);
        }
    }
    size_t o = (size_t)bc * 289 + oh * 17 + ow0;
    if (IDX == 0) {
        out[o] = wt * s0;
        if (owp < 8) out[o + 1] = wt * s1;
    } else {
        out[o] += wt * s0;
        if (owp < 8) out[o + 1] += wt * s1;
    }
}

// ---------------- bbox pred: conv 3x3 pad1 C->4 (LDS-staged), exp epilogue ----------------
__global__ __launch_bounds__(320) void bp_pred(
    const float* __restrict__ xr, const float* __restrict__ w,
    const float* __restrict__ wb, const float* __restrict__ adj,
    const float* __restrict__ bia, float* __restrict__ outx)
{
    __shared__ float pl[16 * 289];
    __shared__ float wl[16 * 36];
    const int b = blockIdx.x, tid = threadIdx.x;
    const int p = tid;
    const int oh = p / 17, ow = p % 17;
    int ihs[3], iws[3]; bool okh[3], okw[3];
#pragma unroll
    for (int k = 0; k < 3; k++) {
        int ih = oh - 1 + k; okh[k] = (unsigned)ih < 17u; ihs[k] = okh[k] ? ih : 0;
        int iw = ow - 1 + k; okw[k] = (unsigned)iw < 17u; iws[k] = okw[k] ? iw : 0;
    }
    float acc0 = 0.f, acc1 = 0.f, acc2 = 0.f, acc3 = 0.f;
    const float* xb = xr + (size_t)b * 256 * 289;
#pragma unroll 1
    for (int c0 = 0; c0 < 256; c0 += 16) {
        __syncthreads();
        for (int i = tid; i < 16 * 289; i += 320) pl[i] = xb[(size_t)c0 * 289 + i];
        for (int i = tid; i < 576; i += 320) {
            int ci = i / 36, r = i - ci * 36;
            int co = r / 9, k = r - co * 9;
            wl[ci * 36 + k * 4 + co] = w[((size_t)co * 256 + c0 + ci) * 9 + k];
        }
        __syncthreads();
        if (p < 289) {
#pragma unroll 1
            for (int ci = 0; ci < 16; ci++) {
                const float* plane = &pl[ci * 289];
#pragma unroll
                for (int kh = 0; kh < 3; kh++)
#pragma unroll
                    for (int kw = 0; kw < 3; kw++) {
                        float v = plane[ihs[kh] * 17 + iws[kw]];
                        v = (okh[kh] && okw[kw]) ? v : 0.0f;
                        const float* wk = &wl[ci * 36 + (kh * 3 + kw) * 4];
                        acc0 = fmaf(v, wk[0], acc0);
                        acc1 = fmaf(v, wk[1], acc1);
                        acc2 = fmaf(v, wk[2], acc2);
                        acc3 = fmaf(v, wk[3], acc3);
                    }
            }
        }
    }
    if (p < 289) {
        float ad = adj[0];
        float t0 = fmaf(ad, acc0 + wb[0], bia[0]);
        float t1 = fmaf(ad, acc1 + wb[1], bia[1]);
        float t2 = fmaf(ad, acc2 + wb[2], bia[2]);
        float t3 = fmaf(ad, acc3 + wb[3], bia[3]);
        size_t ob = (size_t)b * 4 * 289 + p;
        outx[ob]           = expf(fminf(t0, 4.7f));
        outx[ob + 289]     = expf(fminf(t1, 4.7f));
        outx[ob + 2 * 289] = expf(fminf(t2, 4.7f));
        outx[ob + 3 * 289] = expf(fminf(t3, 4.7f));
    }
}

// ---------------- cls pred: conv 3x3 pad1 C->1 (LDS-staged) ----------------
__global__ __launch_bounds__(320) void cp_pred(
    const float* __restrict__ cfeat, const float* __restrict__ w,
    const float* __restrict__ wb, float* __restrict__ outc)
{
    __shared__ float pl[16 * 289];
    __shared__ float wl[16 * 9];
    const int b = blockIdx.x, tid = threadIdx.x;
    const int p = tid;
    const int oh = p / 17, ow = p % 17;
    int ihs[3], iws[3]; bool okh[3], okw[3];
#pragma unroll
    for (int k = 0; k < 3; k++) {
        int ih = oh - 1 + k; okh[k] = (unsigned)ih < 17u; ihs[k] = okh[k] ? ih : 0;
        int iw = ow - 1 + k; okw[k] = (unsigned)iw < 17u; iws[k] = okw[k] ? iw : 0;
    }
    float acc = 0.f;
    const float* xb = cfeat + (size_t)b * 256 * 289;
#pragma unroll 1
    for (int c0 = 0; c0 < 256; c0 += 16) {
        __syncthreads();
        for (int i = tid; i < 16 * 289; i += 320) pl[i] = xb[(size_t)c0 * 289 + i];
        for (int i = tid; i < 144; i += 320) {
            int ci = i / 9, k = i - ci * 9;
            wl[ci * 9 + k] = w[((size_t)(c0 + ci)) * 9 + k];
        }
        __syncthreads();
        if (p < 289) {
#pragma unroll 1
            for (int ci = 0; ci < 16; ci++) {
                const float* plane = &pl[ci * 289];
                const float* wr = &wl[ci * 9];
#pragma unroll
                for (int kh = 0; kh < 3; kh++)
#pragma unroll
                    for (int kw = 0; kw < 3; kw++) {
                        float v = plane[ihs[kh] * 17 + iws[kw]];
                        v = (okh[kh] && okw[kw]) ? v : 0.0f;
                        acc = fmaf(v, wr[kh * 3 + kw], acc);
                    }
            }
        }
    }
    if (p < 289) outc[(size_t)b * 289 + p] = 0.1f * (acc + wb[0]);
}

// ---------------- host launch ----------------
extern "C" void kernel_launch(void* const* d_in, const int* in_sizes, int n_in,
                              void* d_out, int out_size, void* d_ws, size_t ws_size,
                              hipStream_t stream)
{
    (void)in_sizes; (void)n_in; (void)out_size; (void)ws_size;
    const float* search = (const float*)d_in[0];
    const float* kern   = (const float*)d_in[1];
    const float* cls_mw = (const float*)d_in[2];
    const float* reg_mw = (const float*)d_in[7];
    const float* cls_dww = (const float*)d_in[12];
    const float* reg_dww = (const float*)d_in[13];
    const float* btw = (const float*)d_in[14];
    const float* ctw = (const float*)d_in[19];
    const float* bpw = (const float*)d_in[24];
    const float* bpb = (const float*)d_in[25];
    const float* cpw = (const float*)d_in[26];
    const float* cpb = (const float*)d_in[27];
    const float* adj = (const float*)d_in[28];
    const float* bia = (const float*)d_in[29];

    float* ws  = (float*)d_ws;
    float* out = (float*)d_out;

    ushortT* wt_hi = (ushortT*)(ws + WT_HI);
    ushortT* s_hi  = (ushortT*)(ws + INT_SH);
    ushortT* s_lo  = (ushortT*)(ws + INT_SL);
    ushortT* z_hi  = (ushortT*)(ws + INT_ZH);
    ushortT* z_lo  = (ushortT*)(ws + INT_ZL);
    // tower-phase aliases (search NHWC + wt regions dead by then)
    ushortT* pad_hi = s_hi;
    ushortT* pad_lo = s_lo;

    fold_bn_k<<<1, 256, 0, stream>>>(
        (const float*)d_in[3], (const float*)d_in[4], (const float*)d_in[5], (const float*)d_in[6],
        (const float*)d_in[8], (const float*)d_in[9], (const float*)d_in[10], (const float*)d_in[11],
        (const float*)d_in[15], (const float*)d_in[16], (const float*)d_in[17], (const float*)d_in[18],
        (const float*)d_in[20], (const float*)d_in[21], (const float*)d_in[22], (const float*)d_in[23],
        ws);

    // input transforms (shared across both branches)
    nchw2nhwc_split<<<dim3(31, 8, 64), dim3(32, 8), 0, stream>>>(search, s_hi, s_lo, 961);
    nchw2nhwc_split<<<dim3(8, 8, 64), dim3(32, 8), 0, stream>>>(kern, z_hi, z_lo, 225);

    const size_t WC = (size_t)2304 * 256; // per-conv wt plane stride (ushorts)

    auto branch = [&](const float* mw, const float* sbb, const float* dww, float* dwout) {
        wt_split<<<1536, 256, 0, stream>>>(mw, wt_hi);
        // pair 0: dil (1,1): z 13x13, x 29x29
        mfma_conv<1, 1, 13, 13, 15, 15><<<256, 256, 0, stream>>>(
            z_hi, z_lo, wt_hi + 0 * WC, sbb + 0 * 512, ws + WS_ZB);
        mfma_conv<1, 1, 29, 29, 31, 31><<<896, 256, 0, stream>>>(
            s_hi, s_lo, wt_hi + 1 * WC, sbb + 1 * 512, ws + WS_XB);
        xcorr_one<13, 13, 29, 0><<<16384, 192, 0, stream>>>(ws + WS_ZB, ws + WS_XB, dww, dwout);
        // pair 1: dil (2,1): z 11x13, x 27x29
        mfma_conv<2, 1, 11, 13, 15, 15><<<256, 256, 0, stream>>>(
            z_hi, z_lo, wt_hi + 2 * WC, sbb + 2 * 512, ws + WS_ZB);
        mfma_conv<2, 1, 27, 29, 31, 31><<<896, 256, 0, stream>>>(
            s_hi, s_lo, wt_hi + 3 * WC, sbb + 3 * 512, ws + WS_XB);
        xcorr_one<11, 13, 29, 1><<<16384, 192, 0, stream>>>(ws + WS_ZB, ws + WS_XB, dww, dwout);
        // pair 2: dil (1,2): z 13x11, x 29x27
        mfma_conv<1, 2, 13, 11, 15, 15><<<256, 256, 0, stream>>>(
            z_hi, z_lo, wt_hi + 4 * WC, sbb + 4 * 512, ws + WS_ZB);
        mfma_conv<1, 2, 29, 27, 31, 31><<<896, 256, 0, stream>>>(
            s_hi, s_lo, wt_hi + 5 * WC, sbb + 5 * 512, ws + WS_XB);
        xcorr_one<13, 11, 27, 2><<<16384, 192, 0, stream>>>(ws + WS_ZB, ws + WS_XB, dww, dwout);
    };

    // cls branch -> cls_dw directly in d_out; reg branch -> ws
    branch(cls_mw, ws + SB_CLS, cls_dww, out + O_CDW);
    branch(reg_mw, ws + SB_REG, reg_dww, ws + WS_RDW);

    // ---- towers (MFMA path): search NHWC + wt regions now dead, reuse them ----
    wt_split<<<256, 256, 0, stream>>>(btw, wt_hi);                 // slot 0 = bt
    wt_split<<<256, 256, 0, stream>>>(ctw, wt_hi + WC);            // slot 1 = ct
    zero_pad_k<<<1024, 256, 0, stream>>>(pad_hi, pad_lo);

    // bbox tower: pad(reg_dw) -> mfma conv -> x_reg (d_out), then bp conv + exp -> x (d_out)
    nchw2nhwc_pad_split<<<dim3(10, 8, 64), dim3(32, 8), 0, stream>>>(ws + WS_RDW, pad_hi, pad_lo);
    mfma_conv<1, 1, 17, 17, 19, 19><<<384, 256, 0, stream>>>(
        pad_hi, pad_lo, wt_hi, ws + SB_BT, out + O_XREG);
    bp_pred<<<64, 320, 0, stream>>>(out + O_XREG, bpw, bpb, adj, bia, out + O_X);

    // cls tower: pad(cls_dw) -> mfma conv -> c (ws), then cp conv -> cls (d_out)
    // (border zeros persist from zero_pad_k; interior fully rewritten)
    nchw2nhwc_pad_split<<<dim3(10, 8, 64), dim3(32, 8), 0, stream>>>(out + O_CDW, pad_hi, pad_lo);
    mfma_conv<1, 1, 17, 17, 19, 19><<<384, 256, 0, stream>>>(
        pad_hi, pad_lo, wt_hi + WC, ws + SB_CT, ws + WS_CB);
    cp_pred<<<64, 320, 0, stream>>>(ws + WS_CB, cpw, cpb, out + O_CLS);
}

// Round 10
// 1836.699 us; speedup vs baseline: 1.6160x; 1.5010x over previous
//
#include <hip/hip_runtime.h>
#include <math.h>

typedef unsigned short ushortT;
typedef unsigned int uintT;

using bf8   = __attribute__((ext_vector_type(8))) short;
using f32x4 = __attribute__((ext_vector_type(4))) float;

// ---------------- problem constants ----------------
// B=64, C=256, z=15x15, x=31x31, outputs on 17x17 grid.

// ws float offsets
#define SB_CLS 0
#define SB_REG 3072
#define SB_BT  6144
#define SB_CT  6656
#define WT_HI   ((size_t)8192)
#define WT_LO   (WT_HI + (size_t)1769472)               // reused: bp/cp partial buffers
#define BP_PART WT_LO                                    // 8*64*4*289 = 591,872 floats
#define CP_PART (WT_LO + (size_t)600000)                 // 8*64*289  = 147,968 floats
#define INT_SH  (WT_LO + (size_t)1769472)
#define INT_SL  (INT_SH + (size_t)7872512)               // unused (1-term), kept for layout
#define INT_ZH  (INT_SL + (size_t)7872512)
#define INT_ZL  (INT_ZH + (size_t)1843200)               // unused
#define WS_ZB   (INT_ZL + (size_t)1843200)              // f32 64*256*169
#define WS_XB   (WS_ZB + (size_t)2768896)               // f32 64*256*841
#define WS_RDW  (WS_XB + (size_t)13778944)              // f32 64*256*289
#define WS_CB   WS_XB                                   // cls tower feature reuses XB
// total ws floats = WS_RDW + 4734976 = 44,261,376 (~177 MB)

// d_out float offsets (x, cls, cls_dw, x_reg concatenated)
#define O_X    ((size_t)0)
#define O_CLS  ((size_t)73984)
#define O_CDW  ((size_t)92480)
#define O_XREG ((size_t)4827456)

// ---------------- helpers ----------------
__device__ __forceinline__ ushortT f2bf(float v) {
    uintT u = __float_as_uint(v);
    uintT r = ((u >> 16) & 1u) + 0x7fffu;   // round-to-nearest-even
    return (ushortT)((u + r) >> 16);
}
__device__ __forceinline__ void gl16(const ushortT* g, ushortT* l) {
    __builtin_amdgcn_global_load_lds(
        (const __attribute__((address_space(1))) void*)g,
        (__attribute__((address_space(3))) void*)l, 16, 0, 0);
}

// ---------------- BN folding ----------------
__global__ void fold_bn_k(const float* __restrict__ cg, const float* __restrict__ cb,
                          const float* __restrict__ cm, const float* __restrict__ cv,
                          const float* __restrict__ rg, const float* __restrict__ rb,
                          const float* __restrict__ rm, const float* __restrict__ rv,
                          const float* __restrict__ btg, const float* __restrict__ btb,
                          const float* __restrict__ btm, const float* __restrict__ btv,
                          const float* __restrict__ ctg, const float* __restrict__ ctb,
                          const float* __restrict__ ctm, const float* __restrict__ ctv,
                          float* __restrict__ sb)
{
    int c = threadIdx.x; // 256
    for (int i = 0; i < 6; i++) {
        float s = cg[i*256 + c] * rsqrtf(cv[i*256 + c] + 1e-5f);
        sb[SB_CLS + i*512 + c]       = s;
        sb[SB_CLS + i*512 + 256 + c] = cb[i*256 + c] - cm[i*256 + c] * s;
        float s2 = rg[i*256 + c] * rsqrtf(rv[i*256 + c] + 1e-5f);
        sb[SB_REG + i*512 + c]       = s2;
        sb[SB_REG + i*512 + 256 + c] = rb[i*256 + c] - rm[i*256 + c] * s2;
    }
    float s = btg[c] * rsqrtf(btv[c] + 1e-5f);
    sb[SB_BT + c] = s; sb[SB_BT + 256 + c] = btb[c] - btm[c] * s;
    s = ctg[c] * rsqrtf(ctv[c] + 1e-5f);
    sb[SB_CT + c] = s; sb[SB_CT + 256 + c] = ctb[c] - ctm[c] * s;
}

// ---------------- NCHW f32 -> NHWC bf16 (hi plane only) ----------------
__global__ __launch_bounds__(256) void nchw2nhwc_bf16(
    const float* __restrict__ in, ushortT* __restrict__ hi, int HW)
{
    __shared__ float t[32][33];
    const int b = blockIdx.z, ci0 = blockIdx.y * 32, p0 = blockIdx.x * 32;
    const int tx = threadIdx.x, ty = threadIdx.y;
    for (int i = 0; i < 32; i += 8) {
        int ci = ci0 + ty + i, p = p0 + tx;
        t[ty + i][tx] = (p < HW) ? in[((size_t)(b * 256 + ci)) * HW + p] : 0.0f;
    }
    __syncthreads();
    for (int i = 0; i < 32; i += 8) {
        int p = p0 + ty + i;
        if (p < HW) {
            size_t o = ((size_t)b * HW + p) * 256 + ci0 + tx;
            hi[o] = f2bf(t[tx][ty + i]);
        }
    }
}

// ---------------- NCHW f32 17x17 -> padded 19x19 NHWC bf16 (interior only) ----------------
__global__ __launch_bounds__(256) void nchw2nhwc_pad_bf16(
    const float* __restrict__ in, ushortT* __restrict__ hi)
{
    __shared__ float t[32][33];
    const int b = blockIdx.z, ci0 = blockIdx.y * 32, p0 = blockIdx.x * 32;
    const int tx = threadIdx.x, ty = threadIdx.y;
    for (int i = 0; i < 32; i += 8) {
        int ci = ci0 + ty + i, p = p0 + tx;
        t[ty + i][tx] = (p < 289) ? in[((size_t)(b * 256 + ci)) * 289 + p] : 0.0f;
    }
    __syncthreads();
    for (int i = 0; i < 32; i += 8) {
        int p = p0 + ty + i;
        if (p < 289) {
            int pp = (p / 17 + 1) * 19 + (p % 17 + 1);
            size_t o = ((size_t)b * 361 + pp) * 256 + ci0 + tx;
            hi[o] = f2bf(t[tx][ty + i]);
        }
    }
}

// ---------------- zero padded NHWC buffer (hi only) ----------------
__global__ __launch_bounds__(256) void zero_pad_k(ushortT* __restrict__ hi)
{
    const size_t n16 = (size_t)64 * 361 * 256 / 8;  // uint4 count
    uint4 z; z.x = z.y = z.z = z.w = 0u;
    uint4* h4 = (uint4*)hi;
    for (size_t i = blockIdx.x * 256 + threadIdx.x; i < n16; i += (size_t)gridDim.x * 256)
        h4[i] = z;
}

// ---------------- weight transform: [co][ci][9] -> [co][kidx*256+ci] bf16 ----------------
__global__ __launch_bounds__(256) void wt_split(
    const float* __restrict__ w, ushortT* __restrict__ whi)
{
    const int co = blockIdx.x & 255, conv = blockIdx.x >> 8;
    const float* src = w + ((size_t)conv * 256 + co) * 2304;
    __shared__ float lw[2304];
    const int t = threadIdx.x;
#pragma unroll
    for (int i = 0; i < 9; i++) lw[i * 256 + t] = src[i * 256 + t];
    __syncthreads();
    size_t ob = ((size_t)conv * 256 + co) * 2304;
#pragma unroll
    for (int i = 0; i < 9; i++)
        whi[ob + i * 256 + t] = f2bf(lw[t * 9 + i]);
}

// ---------------- MFMA implicit-GEMM conv (VALID, dilated) + BN + relu ----------------
// A: in_t NHWC bf16 [B][HI][WI][256]; B: wt [co][kidx*256+ci] bf16
// out f32 NCHW [B][256][Ho*Wo]. 1D grid = XT*2*64 blocks (XCD-swizzled), block 256 (4 waves).
// Single-term bf16 (B-rounding was measured below harness floor in R8; A symmetric).
// Round-5 proven structure: BK=64, single buffer, 2 __syncthreads per chunk.
// T2: 16B-chunk XOR swizzle (source-side pre-swizzle for global_load_lds; XOR on ds_read).
template <int DH, int DW, int Ho, int Wo, int HI, int WI>
__global__ __launch_bounds__(256, 4) void mfma_conv(
    const ushortT* __restrict__ ahi, const ushortT* __restrict__ whi,
    const float* __restrict__ sb, float* __restrict__ out)
{
    constexpr int NPOS = Ho * Wo;
    constexpr int XT = (NPOS + 127) / 128;
    constexpr int NBLK = XT * 2 * 64;
    __shared__ __align__(16) ushortT lds[2][8192];   // planes A, B: [128 rows][64 k]

    const int t = threadIdx.x, lane = t & 63, wave = t >> 6;

    // XCD-aware bijective swizzle (NBLK % 8 == 0)
    const int id = blockIdx.x;
    const int nid = (id & 7) * (NBLK >> 3) + (id >> 3);
    const int xt = nid % XT;
    const int rem = nid / XT;
    const int cog = rem & 1;
    const int b = rem >> 1;

    const int m0 = xt * 128;
    const int wrow = wave >> 1, wcol = wave & 1;

    // staging: for q in 0..3, row = q*32 + wave*8 + (lane>>3); stored 16B-chunk = lane&7.
    // Source chunk pre-swizzled: g = (lane&7) ^ (row&7), row&7 == lane>>3 here.
    const int lrow = lane >> 3;
    const int e8 = (((lane & 7) ^ lrow) & 7) * 8;
    int aoh[4], aow[4];
    size_t wrb[4];
#pragma unroll
    for (int q = 0; q < 4; q++) {
        int r = q * 32 + wave * 8 + lrow;
        int p = m0 + r; if (p > NPOS - 1) p = NPOS - 1;
        aoh[q] = p / Wo; aow[q] = p - aoh[q] * Wo;
        wrb[q] = (size_t)(cog * 128 + r) * 2304 + e8;
    }

    f32x4 acc[4][4];
#pragma unroll
    for (int i = 0; i < 4; i++)
#pragma unroll
        for (int j = 0; j < 4; j++) acc[i][j] = (f32x4){0.f, 0.f, 0.f, 0.f};

    const int arow = lane & 15;
    const int sw = arow & 7;                 // read-side XOR (row&7, constant across mt/nt)
    const int lsel = lane >> 4;              // k sub-run selector

#pragma unroll 1
    for (int kidx = 0; kidx < 9; ++kidx) {
        const int kh = kidx / 3, kw = kidx - kh * 3;
        size_t ab[4];
#pragma unroll
        for (int q = 0; q < 4; q++)
            ab[q] = ((size_t)((b * HI) + aoh[q] + DH * kh) * WI + aow[q] + DW * kw) * 256 + e8;
        const size_t wk = (size_t)kidx * 256;
#pragma unroll 1
        for (int s = 0; s < 4; ++s) {
            const int cs = s * 64;
#pragma unroll
            for (int q = 0; q < 4; q++) {
                const int dst = (q * 32 + wave * 8) * 64;   // wave-uniform; HW adds lane*16B
                gl16(ahi + ab[q] + cs, &lds[0][dst]);
                gl16(whi + wrb[q] + wk + cs, &lds[1][dst]);
            }
            __syncthreads();
#pragma unroll
            for (int kk = 0; kk < 2; ++kk) {
                const int koS = (((kk * 4 + lsel) ^ sw) << 3);   // swizzled chunk
                bf8 ah[4], bh[4];
#pragma unroll
                for (int mt = 0; mt < 4; ++mt) {
                    int r = wrow * 64 + mt * 16 + arow;
                    ah[mt] = *(const bf8*)&lds[0][r * 64 + koS];
                }
#pragma unroll
                for (int nt = 0; nt < 4; ++nt) {
                    int r = wcol * 64 + nt * 16 + arow;
                    bh[nt] = *(const bf8*)&lds[1][r * 64 + koS];
                }
#pragma unroll
                for (int mt = 0; mt < 4; ++mt)
#pragma unroll
                    for (int nt = 0; nt < 4; ++nt)
                        acc[mt][nt] = __builtin_amdgcn_mfma_f32_16x16x32_bf16(ah[mt], bh[nt], acc[mt][nt], 0, 0, 0);
            }
            __syncthreads();
        }
    }

    // epilogue: folded BN + relu, f32 NCHW store
#pragma unroll
    for (int nt = 0; nt < 4; ++nt) {
        const int co = cog * 128 + wcol * 64 + nt * 16 + arow;
        const float scl = sb[co], bia = sb[256 + co];
        const size_t ob = ((size_t)b * 256 + co) * NPOS;
#pragma unroll
        for (int mt = 0; mt < 4; ++mt)
#pragma unroll
            for (int r = 0; r < 4; ++r) {
                int p = m0 + wrow * 64 + mt * 16 + (lane >> 4) * 4 + r;
                if (p < NPOS) {
                    float v = fmaf(acc[mt][nt][r], scl, bia);
                    out[ob + p] = v > 0.f ? v : 0.f;
                }
            }
    }
}

// ---------------- depthwise xcorr (one of 3), softmax-weighted accumulate ----------------
template <int HZ_, int WZ_, int WX_, int IDX>
__global__ __launch_bounds__(192) void xcorr_one(
    const float* __restrict__ z, const float* __restrict__ x,
    const float* __restrict__ w3, float* __restrict__ out)
{
    constexpr int HX_ = 16 + HZ_;
    constexpr int NX = HX_ * WX_;
    constexpr int NZ = HZ_ * WZ_;
    __shared__ float xs[NX + 4];
    __shared__ float zs[NZ];
    const int bc = blockIdx.x;
    const float* xp = x + (size_t)bc * NX;
    const float* zp = z + (size_t)bc * NZ;
    for (int i = threadIdx.x; i < NX; i += 192) xs[i] = xp[i];
    for (int i = threadIdx.x; i < NZ; i += 192) zs[i] = zp[i];

    float a = w3[0], b = w3[1], c = w3[2];
    float mx = fmaxf(a, fmaxf(b, c));
    float e0 = expf(a - mx), e1 = expf(b - mx), e2 = expf(c - mx);
    float wt = (IDX == 0 ? e0 : (IDX == 1 ? e1 : e2)) / (e0 + e1 + e2);
    __syncthreads();

    int t = threadIdx.x;
    if (t >= 153) return;
    int oh = t / 9, owp = t % 9, ow0 = owp * 2;
    float s0 = 0.0f, s1 = 0.0f;
#pragma unroll 1
    for (int kh = 0; kh < HZ_; kh++) {
        const float* xr = &xs[(oh + kh) * WX_ + ow0];
        const float* zr = &zs[kh * WZ_];
#pragma unroll
        for (int kw = 0; kw < WZ_; kw++) {
            float zv = zr[kw];
            s0 = fmaf(xr[kw], zv, s0);
            s1 = fmaf(xr[kw + 1], zv, s1);
        }
    }
    size_t o = (size_t)bc * 289 + oh * 17 + ow0;
    if (IDX == 0) {
        out[o] = wt * s0;
        if (owp < 8) out[o + 1] = wt * s1;
    } else {
        out[o] += wt * s0;
        if (owp < 8) out[o + 1] += wt * s1;
    }
}

// ---------------- bbox pred partials: conv 3x3 pad1, 32-ci chunk per block ----------------
// grid 64*8 (b, cg), block 320. partial[cg][b][co][289]
__global__ __launch_bounds__(320) void bp_partial(
    const float* __restrict__ xr, const float* __restrict__ w, float* __restrict__ part)
{
    __shared__ float pl[32 * 289];
    __shared__ float wl[32 * 36];
    const int b = blockIdx.x >> 3, cg = blockIdx.x & 7, tid = threadIdx.x;
    const float* xb = xr + ((size_t)b * 256 + cg * 32) * 289;
    for (int i = tid; i < 32 * 289; i += 320) pl[i] = xb[i];
    for (int i = tid; i < 32 * 36; i += 320) {
        int ci = i / 36, r = i - ci * 36;
        int co = r / 9, k = r - co * 9;
        wl[ci * 36 + k * 4 + co] = w[((size_t)co * 256 + cg * 32 + ci) * 9 + k];
    }
    __syncthreads();
    const int p = tid;
    if (p >= 289) return;
    const int oh = p / 17, ow = p % 17;
    int ihs[3], iws[3]; bool okh[3], okw[3];
#pragma unroll
    for (int k = 0; k < 3; k++) {
        int ih = oh - 1 + k; okh[k] = (unsigned)ih < 17u; ihs[k] = okh[k] ? ih : 0;
        int iw = ow - 1 + k; okw[k] = (unsigned)iw < 17u; iws[k] = okw[k] ? iw : 0;
    }
    float a0 = 0.f, a1 = 0.f, a2 = 0.f, a3 = 0.f;
#pragma unroll 1
    for (int ci = 0; ci < 32; ci++) {
        const float* plane = &pl[ci * 289];
#pragma unroll
        for (int kh = 0; kh < 3; kh++)
#pragma unroll
            for (int kw = 0; kw < 3; kw++) {
                float v = plane[ihs[kh] * 17 + iws[kw]];
                v = (okh[kh] && okw[kw]) ? v : 0.0f;
                const float* wk = &wl[ci * 36 + (kh * 3 + kw) * 4];
                a0 = fmaf(v, wk[0], a0);
                a1 = fmaf(v, wk[1], a1);
                a2 = fmaf(v, wk[2], a2);
                a3 = fmaf(v, wk[3], a3);
            }
    }
    size_t ob = (((size_t)cg * 64 + b) * 4) * 289 + p;
    part[ob]           = a0;
    part[ob + 289]     = a1;
    part[ob + 2 * 289] = a2;
    part[ob + 3 * 289] = a3;
}

// grid 64, block 320: sum partials, bias, exp
__global__ __launch_bounds__(320) void bp_final(
    const float* __restrict__ part, const float* __restrict__ wb,
    const float* __restrict__ adj, const float* __restrict__ bia, float* __restrict__ outx)
{
    const int b = blockIdx.x, p = threadIdx.x;
    if (p >= 289) return;
    float ad = adj[0];
#pragma unroll
    for (int co = 0; co < 4; co++) {
        float s = 0.f;
#pragma unroll
        for (int cg = 0; cg < 8; cg++)
            s += part[(((size_t)cg * 64 + b) * 4 + co) * 289 + p];
        float t2 = fmaf(ad, s + wb[co], bia[co]);
        outx[((size_t)b * 4 + co) * 289 + p] = expf(fminf(t2, 4.7f));
    }
}

// ---------------- cls pred partials ----------------
__global__ __launch_bounds__(320) void cp_partial(
    const float* __restrict__ cfeat, const float* __restrict__ w, float* __restrict__ part)
{
    __shared__ float pl[32 * 289];
    __shared__ float wl[32 * 9];
    const int b = blockIdx.x >> 3, cg = blockIdx.x & 7, tid = threadIdx.x;
    const float* xb = cfeat + ((size_t)b * 256 + cg * 32) * 289;
    for (int i = tid; i < 32 * 289; i += 320) pl[i] = xb[i];
    for (int i = tid; i < 32 * 9; i += 320) {
        int ci = i / 9, k = i - ci * 9;
        wl[ci * 9 + k] = w[((size_t)(cg * 32 + ci)) * 9 + k];
    }
    __syncthreads();
    const int p = tid;
    if (p >= 289) return;
    const int oh = p / 17, ow = p % 17;
    int ihs[3], iws[3]; bool okh[3], okw[3];
#pragma unroll
    for (int k = 0; k < 3; k++) {
        int ih = oh - 1 + k; okh[k] = (unsigned)ih < 17u; ihs[k] = okh[k] ? ih : 0;
        int iw = ow - 1 + k; okw[k] = (unsigned)iw < 17u; iws[k] = okw[k] ? iw : 0;
    }
    float acc = 0.f;
#pragma unroll 1
    for (int ci = 0; ci < 32; ci++) {
        const float* plane = &pl[ci * 289];
        const float* wr = &wl[ci * 9];
#pragma unroll
        for (int kh = 0; kh < 3; kh++)
#pragma unroll
            for (int kw = 0; kw < 3; kw++) {
                float v = plane[ihs[kh] * 17 + iws[kw]];
                v = (okh[kh] && okw[kw]) ? v : 0.0f;
                acc = fmaf(v, wr[kh * 3 + kw], acc);
            }
    }
    part[((size_t)cg * 64 + b) * 289 + p] = acc;
}

__global__ __launch_bounds__(320) void cp_final(
    const float* __restrict__ part, const float* __restrict__ wb, float* __restrict__ outc)
{
    const int b = blockIdx.x, p = threadIdx.x;
    if (p >= 289) return;
    float s = 0.f;
#pragma unroll
    for (int cg = 0; cg < 8; cg++)
        s += part[((size_t)cg * 64 + b) * 289 + p];
    outc[(size_t)b * 289 + p] = 0.1f * (s + wb[0]);
}

// ---------------- host launch ----------------
extern "C" void kernel_launch(void* const* d_in, const int* in_sizes, int n_in,
                              void* d_out, int out_size, void* d_ws, size_t ws_size,
                              hipStream_t stream)
{
    (void)in_sizes; (void)n_in; (void)out_size; (void)ws_size;
    const float* search = (const float*)d_in[0];
    const float* kern   = (const float*)d_in[1];
    const float* cls_mw = (const float*)d_in[2];
    const float* reg_mw = (const float*)d_in[7];
    const float* cls_dww = (const float*)d_in[12];
    const float* reg_dww = (const float*)d_in[13];
    const float* btw = (const float*)d_in[14];
    const float* ctw = (const float*)d_in[19];
    const float* bpw = (const float*)d_in[24];
    const float* bpb = (const float*)d_in[25];
    const float* cpw = (const float*)d_in[26];
    const float* cpb = (const float*)d_in[27];
    const float* adj = (const float*)d_in[28];
    const float* bia = (const float*)d_in[29];

    float* ws  = (float*)d_ws;
    float* out = (float*)d_out;

    ushortT* wt_hi = (ushortT*)(ws + WT_HI);
    ushortT* s_hi  = (ushortT*)(ws + INT_SH);
    ushortT* z_hi  = (ushortT*)(ws + INT_ZH);
    // tower-phase alias (search NHWC region dead by then)
    ushortT* pad_hi = s_hi;

    fold_bn_k<<<1, 256, 0, stream>>>(
        (const float*)d_in[3], (const float*)d_in[4], (const float*)d_in[5], (const float*)d_in[6],
        (const float*)d_in[8], (const float*)d_in[9], (const float*)d_in[10], (const float*)d_in[11],
        (const float*)d_in[15], (const float*)d_in[16], (const float*)d_in[17], (const float*)d_in[18],
        (const float*)d_in[20], (const float*)d_in[21], (const float*)d_in[22], (const float*)d_in[23],
        ws);

    // input transforms (shared across both branches)
    nchw2nhwc_bf16<<<dim3(31, 8, 64), dim3(32, 8), 0, stream>>>(search, s_hi, 961);
    nchw2nhwc_bf16<<<dim3(8, 8, 64), dim3(32, 8), 0, stream>>>(kern, z_hi, 225);

    const size_t WC = (size_t)2304 * 256; // per-conv wt plane stride (ushorts)

    auto branch = [&](const float* mw, const float* sbb, const float* dww, float* dwout) {
        wt_split<<<1536, 256, 0, stream>>>(mw, wt_hi);
        // pair 0: dil (1,1): z 13x13, x 29x29
        mfma_conv<1, 1, 13, 13, 15, 15><<<256, 256, 0, stream>>>(
            z_hi, wt_hi + 0 * WC, sbb + 0 * 512, ws + WS_ZB);
        mfma_conv<1, 1, 29, 29, 31, 31><<<896, 256, 0, stream>>>(
            s_hi, wt_hi + 1 * WC, sbb + 1 * 512, ws + WS_XB);
        xcorr_one<13, 13, 29, 0><<<16384, 192, 0, stream>>>(ws + WS_ZB, ws + WS_XB, dww, dwout);
        // pair 1: dil (2,1): z 11x13, x 27x29
        mfma_conv<2, 1, 11, 13, 15, 15><<<256, 256, 0, stream>>>(
            z_hi, wt_hi + 2 * WC, sbb + 2 * 512, ws + WS_ZB);
        mfma_conv<2, 1, 27, 29, 31, 31><<<896, 256, 0, stream>>>(
            s_hi, wt_hi + 3 * WC, sbb + 3 * 512, ws + WS_XB);
        xcorr_one<11, 13, 29, 1><<<16384, 192, 0, stream>>>(ws + WS_ZB, ws + WS_XB, dww, dwout);
        // pair 2: dil (1,2): z 13x11, x 29x27
        mfma_conv<1, 2, 13, 11, 15, 15><<<256, 256, 0, stream>>>(
            z_hi, wt_hi + 4 * WC, sbb + 4 * 512, ws + WS_ZB);
        mfma_conv<1, 2, 29, 27, 31, 31><<<896, 256, 0, stream>>>(
            s_hi, wt_hi + 5 * WC, sbb + 5 * 512, ws + WS_XB);
        xcorr_one<13, 11, 27, 2><<<16384, 192, 0, stream>>>(ws + WS_ZB, ws + WS_XB, dww, dwout);
    };

    // cls branch -> cls_dw directly in d_out; reg branch -> ws
    branch(cls_mw, ws + SB_CLS, cls_dww, out + O_CDW);
    branch(reg_mw, ws + SB_REG, reg_dww, ws + WS_RDW);

    // ---- towers (MFMA path): search NHWC + wt regions now dead, reuse them ----
    wt_split<<<256, 256, 0, stream>>>(btw, wt_hi);                 // slot 0 = bt
    wt_split<<<256, 256, 0, stream>>>(ctw, wt_hi + WC);            // slot 1 = ct
    zero_pad_k<<<1024, 256, 0, stream>>>(pad_hi);

    // bbox tower: pad(reg_dw) -> mfma conv -> x_reg (d_out), then bp partial/final -> x (d_out)
    nchw2nhwc_pad_bf16<<<dim3(10, 8, 64), dim3(32, 8), 0, stream>>>(ws + WS_RDW, pad_hi);
    mfma_conv<1, 1, 17, 17, 19, 19><<<384, 256, 0, stream>>>(
        pad_hi, wt_hi, ws + SB_BT, out + O_XREG);
    bp_partial<<<512, 320, 0, stream>>>(out + O_XREG, bpw, ws + BP_PART);
    bp_final<<<64, 320, 0, stream>>>(ws + BP_PART, bpb, adj, bia, out + O_X);

    // cls tower: pad(cls_dw) -> mfma conv -> c (ws), then cp partial/final -> cls (d_out)
    // (border zeros persist from zero_pad_k; interior fully rewritten)
    nchw2nhwc_pad_bf16<<<dim3(10, 8, 64), dim3(32, 8), 0, stream>>>(out + O_CDW, pad_hi);
    mfma_conv<1, 1, 17, 17, 19, 19><<<384, 256, 0, stream>>>(
        pad_hi, wt_hi + WC, ws + SB_CT, ws + WS_CB);
    cp_partial<<<512, 320, 0, stream>>>(ws + WS_CB, cpw, ws + CP_PART);
    cp_final<<<64, 320, 0, stream>>>(ws + CP_PART, cpb, out + O_CLS);
}